// Round 12
// baseline (297.110 us; speedup 1.0000x reference)
//
#include <hip/hip_runtime.h>
#include <hip/hip_bf16.h>

#define HDIM 128
#define NG 8      // key-range groups
#define NB 32     // edge chunks

typedef unsigned short u16;
typedef unsigned int u32;
typedef __attribute__((ext_vector_type(8))) short bf16x8;
typedef __attribute__((ext_vector_type(4))) float f32x4;

__device__ __forceinline__ float bf2f(u16 u) {
  union { u32 i; float f; } x; x.i = ((u32)u) << 16; return x.f;
}
__device__ __forceinline__ u16 f2bf(float f) {
  union { float f; u32 i; } x; x.f = f;
  u32 r = x.i + 0x7fffu + ((x.i >> 16) & 1u);
  return (u16)(r >> 16);
}

static __device__ __forceinline__ int dmin(int a, int b) { return a < b ? a : b; }

// ---- atomic-free CSR phase 1: per-(range,chunk) LDS histogram ----
__global__ __launch_bounds__(1024) void k_hist2(const int* __restrict__ src, const int* __restrict__ dst,
                                                int* __restrict__ cnt, int E, int NF, int NM) {
  __shared__ int h[15104];
  int g = blockIdx.x & (NG - 1);
  int c = blockIdx.x >> 3;
  int t = threadIdx.x;
  int NFg = (NF + NG - 1) / NG, NMg = (NM + NG - 1) / NG;
  int loF = g * NFg, hiF = dmin(NF, loF + NFg);
  int loM = g * NMg, hiM = dmin(NM, loM + NMg);
  int nb = NFg + NMg;
  for (int j = t; j < nb; j += 1024) h[j] = 0;
  __syncthreads();
  int Epc = (E + NB - 1) / NB;
  int c0 = c * Epc, c1 = dmin(E, c0 + Epc);
  for (int i = c0 + t; i < c1; i += 1024) {
    int s = src[i], d = dst[i];
    if (s >= loF && s < hiF) atomicAdd(&h[s - loF], 1);
    if (d >= loM && d < hiM) atomicAdd(&h[NFg + (d - loM)], 1);
  }
  __syncthreads();
  size_t K = (size_t)NF + NM;
  int* cc = cnt + (size_t)c * K;
  for (int j = t; j < NFg; j += 1024) {
    int k = loF + j;
    if (k < hiF) cc[k] = h[j];
  }
  for (int j = t; j < NMg; j += 1024) {
    int k = loM + j;
    if (k < hiM) cc[NF + k] = h[NFg + j];
  }
}

// ---- merged per-key chunk scan (in-place) + degree + chunk-local rowptr scan ----
__global__ __launch_bounds__(256) void k_scan_chunks3(int* __restrict__ cnt, int NF, int NM, int nchf,
                                                      int* __restrict__ rp_f, int* __restrict__ rp_m,
                                                      int* __restrict__ part_f, int* __restrict__ part_m) {
  __shared__ int sm[256];
  int K = NF + NM;
  int t = threadIdx.x;
  bool isM = (int)blockIdx.x >= nchf;
  int b = isM ? (blockIdx.x - nchf) : blockIdx.x;
  int off = isM ? NF : 0;
  int n = isM ? NM : NF;
  int* rowptr = isM ? rp_m : rp_f;
  int* part = isM ? part_m : part_f;
  int base = b * 1024 + t * 4;
  int v0 = 0, v1 = 0, v2 = 0, v3 = 0;
  if (base + 3 < n && (((off + base) & 3) == 0) && ((K & 3) == 0)) {
    int s0 = 0, s1 = 0, s2 = 0, s3 = 0;
    int* p0 = cnt + off + base;
    #pragma unroll 4
    for (int c = 0; c < NB; ++c) {
      int4* p = (int4*)(p0 + (size_t)c * K);
      int4 x = *p;
      *p = make_int4(s0, s1, s2, s3);
      s0 += x.x; s1 += x.y; s2 += x.z; s3 += x.w;
    }
    v0 = s0; v1 = s1; v2 = s2; v3 = s3;
  } else {
    #pragma unroll
    for (int i = 0; i < 4; ++i) {
      int kl = base + i;
      int s = 0;
      if (kl < n) {
        for (int c = 0; c < NB; ++c) {
          int* p = cnt + (size_t)c * K + off + kl;
          int x = *p; *p = s; s += x;
        }
      }
      if (i == 0) v0 = s; else if (i == 1) v1 = s; else if (i == 2) v2 = s; else v3 = s;
    }
  }
  int s = v0 + v1 + v2 + v3;
  sm[t] = s;
  __syncthreads();
  for (int off2 = 1; off2 < 256; off2 <<= 1) {
    int x = (t >= off2) ? sm[t - off2] : 0;
    __syncthreads();
    sm[t] += x;
    __syncthreads();
  }
  int excl = sm[t] - s;
  if (t == 255) part[b] = sm[255];
  if (base + 0 < n) rowptr[base + 0] = excl;
  if (base + 1 < n) rowptr[base + 1] = excl + v0;
  if (base + 2 < n) rowptr[base + 2] = excl + v0 + v1;
  if (base + 3 < n) rowptr[base + 3] = excl + v0 + v1 + v2;
}

// merged part-scan: block 0 -> part_f (nchf entries), block 1 -> part_m
__global__ __launch_bounds__(256) void k_scan_part2(int* __restrict__ part_f, int nchf,
                                                    int* __restrict__ part_m, int nchm) {
  __shared__ int sm[256];
  int t = threadIdx.x;
  int* part = blockIdx.x ? part_m : part_f;
  int nb = blockIdx.x ? nchm : nchf;
  int s = (t < nb) ? part[t] : 0;
  sm[t] = s;
  __syncthreads();
  for (int off = 1; off < 256; off <<= 1) {
    int x = (t >= off) ? sm[t - off] : 0;
    __syncthreads();
    sm[t] += x;
    __syncthreads();
  }
  if (t < nb) part[t] = sm[t] - s;
}

// merged add-off for both rowptrs
__global__ __launch_bounds__(256) void k_add_off2(int* __restrict__ rp_f, const int* __restrict__ part_f, int NF,
                                                  int* __restrict__ rp_m, const int* __restrict__ part_m, int NM,
                                                  int total) {
  int i = blockIdx.x * 256 + threadIdx.x;
  int s = gridDim.x * 256;
  int tot = NF + NM;
  for (; i < tot; i += s) {
    if (i < NF) rp_f[i] += part_f[i >> 10];
    else { int j = i - NF; rp_m[j] += part_m[j >> 10]; }
  }
  if (blockIdx.x == 0 && threadIdx.x == 0) { rp_f[NF] = total; rp_m[NM] = total; }
}

// ---- phase 3: atomic-free scatter via LDS cursors (slots pre-reserved) ----
__global__ __launch_bounds__(1024) void k_scatter2(const int* __restrict__ src, const int* __restrict__ dst,
                                                   const int* __restrict__ rp_f, const int* __restrict__ rp_m,
                                                   const int* __restrict__ cnt,
                                                   int* __restrict__ col_f, int* __restrict__ col_m,
                                                   int E, int NF, int NM) {
  __shared__ int cur[15104];
  int g = blockIdx.x & (NG - 1);
  int c = blockIdx.x >> 3;
  int t = threadIdx.x;
  int NFg = (NF + NG - 1) / NG, NMg = (NM + NG - 1) / NG;
  int loF = g * NFg, hiF = dmin(NF, loF + NFg);
  int loM = g * NMg, hiM = dmin(NM, loM + NMg);
  size_t K = (size_t)NF + NM;
  const int* cc = cnt + (size_t)c * K;
  for (int j = t; j < NFg; j += 1024) {
    int k = loF + j;
    if (k < hiF) cur[j] = rp_f[k] + cc[k];
  }
  for (int j = t; j < NMg; j += 1024) {
    int k = loM + j;
    if (k < hiM) cur[NFg + j] = rp_m[k] + cc[NF + k];
  }
  __syncthreads();
  int Epc = (E + NB - 1) / NB;
  int c0 = c * Epc, c1 = dmin(E, c0 + Epc);
  for (int i = c0 + t; i < c1; i += 1024) {
    int s = src[i], d = dst[i];
    if (s >= loF && s < hiF) {
      int p = atomicAdd(&cur[s - loF], 1);
      col_f[p] = d;
    }
    if (d >= loM && d < hiM) {
      int p = atomicAdd(&cur[NFg + (d - loM)], 1);
      col_m[p] = s;
    }
  }
}

// merged: weight f32->bf16 conversion (106496 elems) + input projections
__global__ __launch_bounds__(256) void k_projw(const float* __restrict__ xf, const float* __restrict__ Wf,
                                               const float* __restrict__ bfp, const float* __restrict__ xm,
                                               const float* __restrict__ Wm, const float* __restrict__ bmp,
                                               u16* __restrict__ outf, u16* __restrict__ outm,
                                               int NF, int NM,
                                               const float* __restrict__ s0, const float* __restrict__ s1,
                                               const float* __restrict__ s2, const float* __restrict__ s3,
                                               const float* __restrict__ s4, const float* __restrict__ s5,
                                               const float* __restrict__ s6, u16* __restrict__ wdst) {
  __shared__ float Wfs[128 * 9];
  __shared__ float Wms[128 * 5];
  __shared__ float bsf[128];
  __shared__ float bsm[128];
  int t = threadIdx.x;
  for (int i = t; i < 128 * 8; i += 256) {
    int c = i >> 3, k = i & 7;
    Wfs[c * 9 + k] = Wf[i];
  }
  for (int i = t; i < 128 * 5; i += 256) {
    int c = i / 5, k = i - c * 5;
    Wms[c * 5 + k] = Wm[i];
  }
  for (int i = t; i < 128; i += 256) { bsf[i] = bfp[i]; bsm[i] = bmp[i]; }
  __syncthreads();
  const int W2N = 106496;
  int totF = NF * 64;
  int tot = W2N + totF + NM * 64;
  int idx = blockIdx.x * 256 + t;
  int gs = gridDim.x * 256;
  for (; idx < tot; idx += gs) {
    if (idx < W2N) {
      int i = idx;
      const float* s; int off = i;
      if (i < 16384) { s = s0; }
      else if (i < 32768) { s = s1; off = i - 16384; }
      else if (i < 49152) { s = s2; off = i - 32768; }
      else if (i < 65536) { s = s3; off = i - 49152; }
      else if (i < 81920) { s = s4; off = i - 65536; }
      else if (i < 98304) { s = s5; off = i - 81920; }
      else { s = s6; off = i - 98304; }
      wdst[i] = f2bf(s[off]);
    } else if (idx < W2N + totF) {
      int k2 = idx - W2N;
      int row = k2 >> 6, cp = (k2 & 63) * 2;
      float a0 = bsf[cp], a1 = bsf[cp + 1];
      const float* xr = xf + (size_t)row * 8;
      #pragma unroll
      for (int k = 0; k < 8; ++k) {
        float xv = xr[k];
        a0 += Wfs[cp * 9 + k] * xv;
        a1 += Wfs[(cp + 1) * 9 + k] * xv;
      }
      a0 = fmaxf(a0, 0.f); a1 = fmaxf(a1, 0.f);
      u32 pk = (u32)f2bf(a0) | ((u32)f2bf(a1) << 16);
      *(u32*)(outf + (size_t)row * HDIM + cp) = pk;
    } else {
      int k2 = idx - W2N - totF;
      int row = k2 >> 6, cp = (k2 & 63) * 2;
      float a0 = bsm[cp], a1 = bsm[cp + 1];
      const float* xr = xm + (size_t)row * 5;
      #pragma unroll
      for (int k = 0; k < 5; ++k) {
        float xv = xr[k];
        a0 += Wms[cp * 5 + k] * xv;
        a1 += Wms[(cp + 1) * 5 + k] * xv;
      }
      a0 = fmaxf(a0, 0.f); a1 = fmaxf(a1, 0.f);
      u32 pk = (u32)f2bf(a0) | ((u32)f2bf(a1) << 16);
      *(u32*)(outm + (size_t)row * HDIM + cp) = pk;
    }
  }
}

// Mean aggregation, 16-lane groups, 256B rows (fund->manager agg)
__global__ __launch_bounds__(256) void k_agg2(const u16* __restrict__ feat, const int* __restrict__ rowptr,
                                              const int* __restrict__ col, u16* __restrict__ out, int ndst) {
  int t = threadIdx.x;
  int grp = t >> 4, lc = t & 15;
  int nd = blockIdx.x * 16 + grp;
  if (nd >= ndst) return;
  int s0 = rowptr[nd], s1 = rowptr[nd + 1];
  float a0=0.f,a1=0.f,a2=0.f,a3=0.f,a4=0.f,a5=0.f,a6=0.f,a7=0.f;
  const u16* fb = feat + lc * 8;
  int j = s0;
  for (; j + 3 < s1; j += 4) {
    uint4 v0 = *(const uint4*)(fb + (size_t)col[j]     * HDIM);
    uint4 v1 = *(const uint4*)(fb + (size_t)col[j + 1] * HDIM);
    uint4 v2 = *(const uint4*)(fb + (size_t)col[j + 2] * HDIM);
    uint4 v3 = *(const uint4*)(fb + (size_t)col[j + 3] * HDIM);
    a0 += bf2f((u16)v0.x) + bf2f((u16)v1.x) + bf2f((u16)v2.x) + bf2f((u16)v3.x);
    a1 += bf2f((u16)(v0.x>>16)) + bf2f((u16)(v1.x>>16)) + bf2f((u16)(v2.x>>16)) + bf2f((u16)(v3.x>>16));
    a2 += bf2f((u16)v0.y) + bf2f((u16)v1.y) + bf2f((u16)v2.y) + bf2f((u16)v3.y);
    a3 += bf2f((u16)(v0.y>>16)) + bf2f((u16)(v1.y>>16)) + bf2f((u16)(v2.y>>16)) + bf2f((u16)(v3.y>>16));
    a4 += bf2f((u16)v0.z) + bf2f((u16)v1.z) + bf2f((u16)v2.z) + bf2f((u16)v3.z);
    a5 += bf2f((u16)(v0.z>>16)) + bf2f((u16)(v1.z>>16)) + bf2f((u16)(v2.z>>16)) + bf2f((u16)(v3.z>>16));
    a6 += bf2f((u16)v0.w) + bf2f((u16)v1.w) + bf2f((u16)v2.w) + bf2f((u16)v3.w);
    a7 += bf2f((u16)(v0.w>>16)) + bf2f((u16)(v1.w>>16)) + bf2f((u16)(v2.w>>16)) + bf2f((u16)(v3.w>>16));
  }
  for (; j < s1; ++j) {
    uint4 v = *(const uint4*)(fb + (size_t)col[j] * HDIM);
    a0 += bf2f((u16)v.x); a1 += bf2f((u16)(v.x >> 16));
    a2 += bf2f((u16)v.y); a3 += bf2f((u16)(v.y >> 16));
    a4 += bf2f((u16)v.z); a5 += bf2f((u16)(v.z >> 16));
    a6 += bf2f((u16)v.w); a7 += bf2f((u16)(v.w >> 16));
  }
  float inv = (s1 > s0) ? 1.f / (float)(s1 - s0) : 0.f;
  uint4 pk;
  pk.x = (u32)f2bf(a0 * inv) | ((u32)f2bf(a1 * inv) << 16);
  pk.y = (u32)f2bf(a2 * inv) | ((u32)f2bf(a3 * inv) << 16);
  pk.z = (u32)f2bf(a4 * inv) | ((u32)f2bf(a5 * inv) << 16);
  pk.w = (u32)f2bf(a6 * inv) | ((u32)f2bf(a7 * inv) << 16);
  *(uint4*)(out + (size_t)nd * HDIM + lc * 8) = pk;
}

// Dual mean aggregation over interleaved [t0|t1] 512B rows; 32-lane groups.
// UNROLL-8 with two accumulator banks: 8 x 512B rows in flight per group
// (deg mean ~10 -> most nodes finish in one fully-parallel round).
__global__ __launch_bounds__(256) void k_aggd(const u16* __restrict__ tc, const int* __restrict__ rowptr,
                                              const int* __restrict__ col, u16* __restrict__ aggc, int ndst) {
  int t = threadIdx.x;
  int grp = t >> 5, lc = t & 31;
  int nd = blockIdx.x * 8 + grp;
  if (nd >= ndst) return;
  int s0 = rowptr[nd], s1 = rowptr[nd + 1];
  float a0=0.f,a1=0.f,a2=0.f,a3=0.f,a4=0.f,a5=0.f,a6=0.f,a7=0.f;
  float b0=0.f,b1=0.f,b2=0.f,b3=0.f,b4=0.f,b5=0.f,b6=0.f,b7=0.f;
  const u16* fb = tc + lc * 8;
  int j = s0;
  for (; j + 7 < s1; j += 8) {
    uint4 v0 = *(const uint4*)(fb + (size_t)col[j]     * 256);
    uint4 v1 = *(const uint4*)(fb + (size_t)col[j + 1] * 256);
    uint4 v2 = *(const uint4*)(fb + (size_t)col[j + 2] * 256);
    uint4 v3 = *(const uint4*)(fb + (size_t)col[j + 3] * 256);
    uint4 v4 = *(const uint4*)(fb + (size_t)col[j + 4] * 256);
    uint4 v5 = *(const uint4*)(fb + (size_t)col[j + 5] * 256);
    uint4 v6 = *(const uint4*)(fb + (size_t)col[j + 6] * 256);
    uint4 v7 = *(const uint4*)(fb + (size_t)col[j + 7] * 256);
    a0 += bf2f((u16)v0.x) + bf2f((u16)v1.x) + bf2f((u16)v2.x) + bf2f((u16)v3.x);
    a1 += bf2f((u16)(v0.x>>16)) + bf2f((u16)(v1.x>>16)) + bf2f((u16)(v2.x>>16)) + bf2f((u16)(v3.x>>16));
    a2 += bf2f((u16)v0.y) + bf2f((u16)v1.y) + bf2f((u16)v2.y) + bf2f((u16)v3.y);
    a3 += bf2f((u16)(v0.y>>16)) + bf2f((u16)(v1.y>>16)) + bf2f((u16)(v2.y>>16)) + bf2f((u16)(v3.y>>16));
    a4 += bf2f((u16)v0.z) + bf2f((u16)v1.z) + bf2f((u16)v2.z) + bf2f((u16)v3.z);
    a5 += bf2f((u16)(v0.z>>16)) + bf2f((u16)(v1.z>>16)) + bf2f((u16)(v2.z>>16)) + bf2f((u16)(v3.z>>16));
    a6 += bf2f((u16)v0.w) + bf2f((u16)v1.w) + bf2f((u16)v2.w) + bf2f((u16)v3.w);
    a7 += bf2f((u16)(v0.w>>16)) + bf2f((u16)(v1.w>>16)) + bf2f((u16)(v2.w>>16)) + bf2f((u16)(v3.w>>16));
    b0 += bf2f((u16)v4.x) + bf2f((u16)v5.x) + bf2f((u16)v6.x) + bf2f((u16)v7.x);
    b1 += bf2f((u16)(v4.x>>16)) + bf2f((u16)(v5.x>>16)) + bf2f((u16)(v6.x>>16)) + bf2f((u16)(v7.x>>16));
    b2 += bf2f((u16)v4.y) + bf2f((u16)v5.y) + bf2f((u16)v6.y) + bf2f((u16)v7.y);
    b3 += bf2f((u16)(v4.y>>16)) + bf2f((u16)(v5.y>>16)) + bf2f((u16)(v6.y>>16)) + bf2f((u16)(v7.y>>16));
    b4 += bf2f((u16)v4.z) + bf2f((u16)v5.z) + bf2f((u16)v6.z) + bf2f((u16)v7.z);
    b5 += bf2f((u16)(v4.z>>16)) + bf2f((u16)(v5.z>>16)) + bf2f((u16)(v6.z>>16)) + bf2f((u16)(v7.z>>16));
    b6 += bf2f((u16)v4.w) + bf2f((u16)v5.w) + bf2f((u16)v6.w) + bf2f((u16)v7.w);
    b7 += bf2f((u16)(v4.w>>16)) + bf2f((u16)(v5.w>>16)) + bf2f((u16)(v6.w>>16)) + bf2f((u16)(v7.w>>16));
  }
  for (; j + 3 < s1; j += 4) {
    uint4 v0 = *(const uint4*)(fb + (size_t)col[j]     * 256);
    uint4 v1 = *(const uint4*)(fb + (size_t)col[j + 1] * 256);
    uint4 v2 = *(const uint4*)(fb + (size_t)col[j + 2] * 256);
    uint4 v3 = *(const uint4*)(fb + (size_t)col[j + 3] * 256);
    a0 += bf2f((u16)v0.x) + bf2f((u16)v1.x) + bf2f((u16)v2.x) + bf2f((u16)v3.x);
    a1 += bf2f((u16)(v0.x>>16)) + bf2f((u16)(v1.x>>16)) + bf2f((u16)(v2.x>>16)) + bf2f((u16)(v3.x>>16));
    a2 += bf2f((u16)v0.y) + bf2f((u16)v1.y) + bf2f((u16)v2.y) + bf2f((u16)v3.y);
    a3 += bf2f((u16)(v0.y>>16)) + bf2f((u16)(v1.y>>16)) + bf2f((u16)(v2.y>>16)) + bf2f((u16)(v3.y>>16));
    a4 += bf2f((u16)v0.z) + bf2f((u16)v1.z) + bf2f((u16)v2.z) + bf2f((u16)v3.z);
    a5 += bf2f((u16)(v0.z>>16)) + bf2f((u16)(v1.z>>16)) + bf2f((u16)(v2.z>>16)) + bf2f((u16)(v3.z>>16));
    a6 += bf2f((u16)v0.w) + bf2f((u16)v1.w) + bf2f((u16)v2.w) + bf2f((u16)v3.w);
    a7 += bf2f((u16)(v0.w>>16)) + bf2f((u16)(v1.w>>16)) + bf2f((u16)(v2.w>>16)) + bf2f((u16)(v3.w>>16));
  }
  for (; j < s1; ++j) {
    uint4 v = *(const uint4*)(fb + (size_t)col[j] * 256);
    a0 += bf2f((u16)v.x); a1 += bf2f((u16)(v.x >> 16));
    a2 += bf2f((u16)v.y); a3 += bf2f((u16)(v.y >> 16));
    a4 += bf2f((u16)v.z); a5 += bf2f((u16)(v.z >> 16));
    a6 += bf2f((u16)v.w); a7 += bf2f((u16)(v.w >> 16));
  }
  a0 += b0; a1 += b1; a2 += b2; a3 += b3;
  a4 += b4; a5 += b5; a6 += b6; a7 += b7;
  float inv = (s1 > s0) ? 1.f / (float)(s1 - s0) : 0.f;
  uint4 pk;
  pk.x = (u32)f2bf(a0 * inv) | ((u32)f2bf(a1 * inv) << 16);
  pk.y = (u32)f2bf(a2 * inv) | ((u32)f2bf(a3 * inv) << 16);
  pk.z = (u32)f2bf(a4 * inv) | ((u32)f2bf(a5 * inv) << 16);
  pk.w = (u32)f2bf(a6 * inv) | ((u32)f2bf(a7 * inv) << 16);
  *(uint4*)(aggc + (size_t)nd * 256 + lc * 8) = pk;
}

// MFMA GEMM, swapped operands (A=W, B=X): lane owns one output row, 4 cols/nt.
__global__ __launch_bounds__(256) void k_ling(const u16* __restrict__ X1, const u16* __restrict__ W1,
                                              const u16* __restrict__ X2, const u16* __restrict__ W2,
                                              const u16* __restrict__ ADD, const float* __restrict__ bias,
                                              u16* __restrict__ out, int n, int do_relu,
                                              int ostride, int astride) {
  int t = threadIdx.x;
  int w = t >> 6, lane = t & 63;
  int lm = lane & 15, lk = (lane >> 4) * 8;
  int cg = (lane >> 4) * 4;
  int row0 = blockIdx.x * 128 + w * 32;
  if (row0 >= n) return;
  int r0 = row0 + lm;       if (r0 >= n) r0 = n - 1;
  int r1 = row0 + 16 + lm;  if (r1 >= n) r1 = n - 1;
  f32x4 acc0[8], acc1[8];
  #pragma unroll
  for (int i = 0; i < 8; ++i) { acc0[i] = (f32x4){0.f,0.f,0.f,0.f}; acc1[i] = (f32x4){0.f,0.f,0.f,0.f}; }
  const u16* Xp = X1;
  const u16* Wp = W1;
  for (int p = 0; p < 2; ++p) {
    #pragma unroll
    for (int ks = 0; ks < 4; ++ks) {
      bf16x8 b0 = *(const bf16x8*)(Xp + (size_t)r0 * 128 + ks * 32 + lk);
      bf16x8 b1 = *(const bf16x8*)(Xp + (size_t)r1 * 128 + ks * 32 + lk);
      #pragma unroll
      for (int nt = 0; nt < 8; ++nt) {
        bf16x8 a = *(const bf16x8*)(Wp + (size_t)(nt * 16 + lm) * 128 + ks * 32 + lk);
        acc0[nt] = __builtin_amdgcn_mfma_f32_16x16x32_bf16(a, b0, acc0[nt], 0, 0, 0);
        acc1[nt] = __builtin_amdgcn_mfma_f32_16x16x32_bf16(a, b1, acc1[nt], 0, 0, 0);
      }
    }
    if (!X2) break;
    Xp = X2;
    Wp = W2;
  }
  #pragma unroll
  for (int half = 0; half < 2; ++half) {
    int m = row0 + half * 16 + lm;
    if (m >= n) break;
    f32x4* acc = half ? acc1 : acc0;
    #pragma unroll
    for (int nt = 0; nt < 8; ++nt) {
      int c = nt * 16 + cg;
      float v0 = acc[nt][0], v1 = acc[nt][1], v2 = acc[nt][2], v3 = acc[nt][3];
      if (bias) {
        float4 bv = *(const float4*)(bias + c);
        v0 += bv.x; v1 += bv.y; v2 += bv.z; v3 += bv.w;
      }
      if (ADD) {
        ushort4 av = *(const ushort4*)(ADD + (size_t)m * astride + c);
        v0 += bf2f(av.x); v1 += bf2f(av.y); v2 += bf2f(av.z); v3 += bf2f(av.w);
      }
      if (do_relu) {
        v0 = fmaxf(v0, 0.f); v1 = fmaxf(v1, 0.f); v2 = fmaxf(v2, 0.f); v3 = fmaxf(v3, 0.f);
      }
      ushort4 pk;
      pk.x = f2bf(v0); pk.y = f2bf(v1); pk.z = f2bf(v2); pk.w = f2bf(v3);
      *(ushort4*)(out + (size_t)m * ostride + c) = pk;
    }
  }
}

// Two independent no-bias GEMMs into interleaved [n][256] buffer.
__global__ __launch_bounds__(256) void k_ling2(const u16* __restrict__ XA, const u16* __restrict__ WA,
                                               const u16* __restrict__ XB, const u16* __restrict__ WB,
                                               u16* __restrict__ out, int n) {
  int nb = gridDim.x >> 1;
  bool second = (int)blockIdx.x >= nb;
  const u16* X = second ? XB : XA;
  const u16* W = second ? WB : WA;
  int bid = second ? (blockIdx.x - nb) : blockIdx.x;
  u16* o = out + (second ? 128 : 0);
  int t = threadIdx.x;
  int w = t >> 6, lane = t & 63;
  int lm = lane & 15, lk = (lane >> 4) * 8;
  int cg = (lane >> 4) * 4;
  int row0 = bid * 128 + w * 32;
  if (row0 >= n) return;
  int r0 = row0 + lm;       if (r0 >= n) r0 = n - 1;
  int r1 = row0 + 16 + lm;  if (r1 >= n) r1 = n - 1;
  f32x4 acc0[8], acc1[8];
  #pragma unroll
  for (int i = 0; i < 8; ++i) { acc0[i] = (f32x4){0.f,0.f,0.f,0.f}; acc1[i] = (f32x4){0.f,0.f,0.f,0.f}; }
  #pragma unroll
  for (int ks = 0; ks < 4; ++ks) {
    bf16x8 b0 = *(const bf16x8*)(X + (size_t)r0 * 128 + ks * 32 + lk);
    bf16x8 b1 = *(const bf16x8*)(X + (size_t)r1 * 128 + ks * 32 + lk);
    #pragma unroll
    for (int nt = 0; nt < 8; ++nt) {
      bf16x8 a = *(const bf16x8*)(W + (size_t)(nt * 16 + lm) * 128 + ks * 32 + lk);
      acc0[nt] = __builtin_amdgcn_mfma_f32_16x16x32_bf16(a, b0, acc0[nt], 0, 0, 0);
      acc1[nt] = __builtin_amdgcn_mfma_f32_16x16x32_bf16(a, b1, acc1[nt], 0, 0, 0);
    }
  }
  #pragma unroll
  for (int half = 0; half < 2; ++half) {
    int m = row0 + half * 16 + lm;
    if (m >= n) break;
    f32x4* acc = half ? acc1 : acc0;
    #pragma unroll
    for (int nt = 0; nt < 8; ++nt) {
      int c = nt * 16 + cg;
      ushort4 pk;
      pk.x = f2bf(acc[nt][0]); pk.y = f2bf(acc[nt][1]);
      pk.z = f2bf(acc[nt][2]); pk.w = f2bf(acc[nt][3]);
      *(ushort4*)(o + (size_t)m * 256 + c) = pk;
    }
  }
}

// Fused f2-GEMM + classifier: f2 tile lives only in per-wave LDS (never HBM).
__global__ __launch_bounds__(256) void k_lingcls(const u16* __restrict__ X1, const u16* __restrict__ W1,
                                                 const u16* __restrict__ ADD, const float* __restrict__ bias,
                                                 const u16* __restrict__ Wc1bf, const float* __restrict__ bc1,
                                                 const float* __restrict__ Wc2, const float* __restrict__ bc2,
                                                 float* __restrict__ out, int n) {
  __shared__ u16 tile[4][32][136];
  int t = threadIdx.x;
  int w = t >> 6, lane = t & 63;
  int lm = lane & 15, lk = (lane >> 4) * 8;
  int cg = (lane >> 4) * 4;
  int row0 = blockIdx.x * 128 + w * 32;
  if (row0 >= n) return;
  int r0 = row0 + lm;       if (r0 >= n) r0 = n - 1;
  int r1 = row0 + 16 + lm;  if (r1 >= n) r1 = n - 1;
  f32x4 acc0[8], acc1[8];
  #pragma unroll
  for (int i = 0; i < 8; ++i) { acc0[i] = (f32x4){0.f,0.f,0.f,0.f}; acc1[i] = (f32x4){0.f,0.f,0.f,0.f}; }
  #pragma unroll
  for (int ks = 0; ks < 4; ++ks) {
    bf16x8 b0 = *(const bf16x8*)(X1 + (size_t)r0 * 128 + ks * 32 + lk);
    bf16x8 b1 = *(const bf16x8*)(X1 + (size_t)r1 * 128 + ks * 32 + lk);
    #pragma unroll
    for (int nt = 0; nt < 8; ++nt) {
      bf16x8 a = *(const bf16x8*)(W1 + (size_t)(nt * 16 + lm) * 128 + ks * 32 + lk);
      acc0[nt] = __builtin_amdgcn_mfma_f32_16x16x32_bf16(a, b0, acc0[nt], 0, 0, 0);
      acc1[nt] = __builtin_amdgcn_mfma_f32_16x16x32_bf16(a, b1, acc1[nt], 0, 0, 0);
    }
  }
  #pragma unroll
  for (int half = 0; half < 2; ++half) {
    int m = row0 + half * 16 + lm;
    if (m >= n) break;
    int lr = half * 16 + lm;
    f32x4* acc = half ? acc1 : acc0;
    #pragma unroll
    for (int nt = 0; nt < 8; ++nt) {
      int c = nt * 16 + cg;
      float4 bv = *(const float4*)(bias + c);
      ushort4 av = *(const ushort4*)(ADD + (size_t)m * 256 + c);
      float v0 = fmaxf(acc[nt][0] + bv.x + bf2f(av.x), 0.f);
      float v1 = fmaxf(acc[nt][1] + bv.y + bf2f(av.y), 0.f);
      float v2 = fmaxf(acc[nt][2] + bv.z + bf2f(av.z), 0.f);
      float v3 = fmaxf(acc[nt][3] + bv.w + bf2f(av.w), 0.f);
      ushort4 pk;
      pk.x = f2bf(v0); pk.y = f2bf(v1); pk.z = f2bf(v2); pk.w = f2bf(v3);
      *(ushort4*)&tile[w][lr][c] = pk;
    }
  }
  #pragma unroll
  for (int half = 0; half < 2; ++half) {
    f32x4 cacc[4];
    #pragma unroll
    for (int i = 0; i < 4; ++i) cacc[i] = (f32x4){0.f, 0.f, 0.f, 0.f};
    #pragma unroll
    for (int ks = 0; ks < 4; ++ks) {
      bf16x8 b = *(const bf16x8*)&tile[w][half * 16 + lm][ks * 32 + lk];
      #pragma unroll
      for (int nt = 0; nt < 4; ++nt) {
        bf16x8 a = *(const bf16x8*)(Wc1bf + (size_t)(nt * 16 + lm) * 128 + ks * 32 + lk);
        cacc[nt] = __builtin_amdgcn_mfma_f32_16x16x32_bf16(a, b, cacc[nt], 0, 0, 0);
      }
    }
    float s0 = 0.f, s1 = 0.f;
    #pragma unroll
    for (int nt = 0; nt < 4; ++nt) {
      int k = nt * 16 + cg;
      float4 bv = *(const float4*)(bc1 + k);
      float4 w0 = *(const float4*)(Wc2 + k);
      float4 w1 = *(const float4*)(Wc2 + 64 + k);
      float h0 = fmaxf(cacc[nt][0] + bv.x, 0.f);
      float h1 = fmaxf(cacc[nt][1] + bv.y, 0.f);
      float h2 = fmaxf(cacc[nt][2] + bv.z, 0.f);
      float h3 = fmaxf(cacc[nt][3] + bv.w, 0.f);
      s0 += h0 * w0.x + h1 * w0.y + h2 * w0.z + h3 * w0.w;
      s1 += h0 * w1.x + h1 * w1.y + h2 * w1.z + h3 * w1.w;
    }
    s0 += __shfl_xor(s0, 16); s1 += __shfl_xor(s1, 16);
    s0 += __shfl_xor(s0, 32); s1 += __shfl_xor(s1, 32);
    int m = row0 + half * 16 + lm;
    if (lane < 16 && m < n) {
      out[(size_t)m * 2 + 0] = s0 + bc2[0];
      out[(size_t)m * 2 + 1] = s1 + bc2[1];
    }
  }
}

static inline int imin(int a, int b) { return a < b ? a : b; }

extern "C" void kernel_launch(void* const* d_in, const int* in_sizes, int n_in,
                              void* d_out, int out_size, void* d_ws, size_t ws_size,
                              hipStream_t stream) {
  const float* x_fund = (const float*)d_in[0];
  const float* x_mgr  = (const float*)d_in[1];
  const int* fm_src   = (const int*)d_in[2];
  const int* fm_dst   = (const int*)d_in[3];
  const float* Wf = (const float*)d_in[4];
  const float* bfb = (const float*)d_in[5];
  const float* Wm = (const float*)d_in[6];
  const float* bm = (const float*)d_in[7];
  const float* Wl_fm0 = (const float*)d_in[8];
  const float* bl_fm0 = (const float*)d_in[9];
  const float* Wr_fm0 = (const float*)d_in[10];
  const float* Wl_mf0 = (const float*)d_in[11];
  const float* bl_mf0 = (const float*)d_in[12];
  const float* Wr_mf0 = (const float*)d_in[13];
  const float* Wl_mf1 = (const float*)d_in[17];
  const float* bl_mf1 = (const float*)d_in[18];
  const float* Wr_mf1 = (const float*)d_in[19];
  const float* Wc1 = (const float*)d_in[20];
  const float* bc1 = (const float*)d_in[21];
  const float* Wc2 = (const float*)d_in[22];
  const float* bc2 = (const float*)d_in[23];
  // (Wl_fm1/bl_fm1/Wr_fm1 at indices 14..16 are dead: m2 is deleted in the reference)

  int NF = in_sizes[0] / 8;
  int NM = in_sizes[1] / 5;
  int E  = in_sizes[2];
  int K  = NF + NM;

  char* ws = (char*)d_ws;
  size_t off = 0;
  auto alloc = [&](size_t bytes) -> char* {
    char* p = ws + off;
    off += (bytes + 255) & ~(size_t)255;
    return p;
  };
  u16* f_b   = (u16*)alloc((size_t)NF * HDIM * 2);
  u16* f1_b  = (u16*)alloc((size_t)NF * HDIM * 2);
  u16* aggc  = (u16*)alloc((size_t)NF * 256 * 2);   // interleaved [aggf0|aggf1]
  u16* m_b   = (u16*)alloc((size_t)NM * HDIM * 2);
  u16* m1_b  = (u16*)alloc((size_t)NM * HDIM * 2);
  u16* tcomb = (u16*)alloc((size_t)NM * 256 * 2);   // interleaved [t0|t1]
  u16* aggm  = (u16*)alloc((size_t)NM * HDIM * 2);
  u16* wbf   = (u16*)alloc((size_t)106496 * 2);
  int* rp_f  = (int*)alloc((size_t)(NF + 1) * 4);
  int* rp_m  = (int*)alloc((size_t)(NM + 1) * 4);
  int* col_f = (int*)alloc((size_t)E * 4);
  int* col_m = (int*)alloc((size_t)E * 4);
  int* cnt   = (int*)alloc((size_t)NB * K * 4);
  int* part_f = (int*)alloc(256 * 4);
  int* part_m = (int*)alloc(256 * 4);
  (void)ws_size; (void)n_in; (void)out_size;

  u16* Wlfm0b = wbf + 0;
  u16* Wrfm0b = wbf + 16384;
  u16* Wlmf0b = wbf + 32768;
  u16* Wrmf0b = wbf + 49152;
  u16* Wlmf1b = wbf + 65536;
  u16* Wrmf1b = wbf + 81920;
  u16* Wc1b   = wbf + 98304;

  int nch_f = (NF + 1023) / 1024;
  int nch_m = (NM + 1023) / 1024;

  // ---- atomic-free CSR build (merged scan pipeline) ----
  k_hist2<<<NG * NB, 1024, 0, stream>>>(fm_src, fm_dst, cnt, E, NF, NM);
  k_scan_chunks3<<<nch_f + nch_m, 256, 0, stream>>>(cnt, NF, NM, nch_f, rp_f, rp_m, part_f, part_m);
  k_scan_part2<<<2, 256, 0, stream>>>(part_f, nch_f, part_m, nch_m);
  k_add_off2<<<(K + 255) / 256, 256, 0, stream>>>(rp_f, part_f, NF, rp_m, part_m, NM, E);
  k_scatter2<<<NG * NB, 1024, 0, stream>>>(fm_src, fm_dst, rp_f, rp_m, cnt, col_f, col_m, E, NF, NM);

  // ---- merged weight conversion + input projections ----
  k_projw<<<4096, 256, 0, stream>>>(x_fund, Wf, bfb, x_mgr, Wm, bm, f_b, m_b, NF, NM,
                                    Wl_fm0, Wr_fm0, Wl_mf0, Wr_mf0, Wl_mf1, Wr_mf1, Wc1, wbf);

  // ---- layer 0, fund->manager: m1 = relu(agg(f)@Wl + m@Wr + bl) ----
  k_agg2<<<(NM + 15) / 16, 256, 0, stream>>>(f_b, rp_m, col_m, aggm, NM);
  k_ling<<<(NM + 127) / 128, 256, 0, stream>>>(aggm, Wlfm0b, m_b, Wrfm0b, nullptr, bl_fm0,
                                               m1_b, NM, 1, 128, 128);

  // ---- t0 = m@Wl_mf0, t1 = m1@Wl_mf1 -> interleaved tcomb (one launch) ----
  k_ling2<<<2 * ((NM + 127) / 128), 256, 0, stream>>>(m_b, Wlmf0b, m1_b, Wlmf1b, tcomb, NM);

  // ---- dual gather, unroll-8 (L3-serviced path) ----
  k_aggd<<<(NF + 7) / 8, 256, 0, stream>>>(tcomb, rp_f, col_f, aggc, NF);

  // ---- f1 = relu(f@Wr_mf0 + aggf0 + bl0) ----
  k_ling<<<(NF + 127) / 128, 256, 0, stream>>>(f_b, Wrmf0b, nullptr, nullptr, aggc, bl_mf0,
                                               f1_b, NF, 1, 128, 256);

  // ---- fused: f2 = relu(f1@Wr_mf1 + aggf1 + bl1) -> LDS -> classifier -> out ----
  k_lingcls<<<(NF + 127) / 128, 256, 0, stream>>>(f1_b, Wrmf1b, aggc + 128, bl_mf1,
                                                  Wc1b, bc1, Wc2, bc2, (float*)d_out, NF);
}

// Round 13
// 289.679 us; speedup vs baseline: 1.0257x; 1.0257x over previous
//
#include <hip/hip_runtime.h>
#include <hip/hip_bf16.h>

#define HDIM 128
#define NG 8      // key-range groups
#define NB 32     // edge chunks

typedef unsigned short u16;
typedef unsigned int u32;
typedef __attribute__((ext_vector_type(8))) short bf16x8;
typedef __attribute__((ext_vector_type(4))) float f32x4;

__device__ __forceinline__ float bf2f(u16 u) {
  union { u32 i; float f; } x; x.i = ((u32)u) << 16; return x.f;
}
__device__ __forceinline__ u16 f2bf(float f) {
  union { float f; u32 i; } x; x.f = f;
  u32 r = x.i + 0x7fffu + ((x.i >> 16) & 1u);
  return (u16)(r >> 16);
}

static __device__ __forceinline__ int dmin(int a, int b) { return a < b ? a : b; }

// ---- atomic-free CSR phase 1: per-(range,chunk) LDS histogram ----
__global__ __launch_bounds__(1024) void k_hist2(const int* __restrict__ src, const int* __restrict__ dst,
                                                int* __restrict__ cnt, int E, int NF, int NM) {
  __shared__ int h[15104];
  int g = blockIdx.x & (NG - 1);
  int c = blockIdx.x >> 3;
  int t = threadIdx.x;
  int NFg = (NF + NG - 1) / NG, NMg = (NM + NG - 1) / NG;
  int loF = g * NFg, hiF = dmin(NF, loF + NFg);
  int loM = g * NMg, hiM = dmin(NM, loM + NMg);
  int nb = NFg + NMg;
  for (int j = t; j < nb; j += 1024) h[j] = 0;
  __syncthreads();
  int Epc = (E + NB - 1) / NB;
  int c0 = c * Epc, c1 = dmin(E, c0 + Epc);
  for (int i = c0 + t; i < c1; i += 1024) {
    int s = src[i], d = dst[i];
    if (s >= loF && s < hiF) atomicAdd(&h[s - loF], 1);
    if (d >= loM && d < hiM) atomicAdd(&h[NFg + (d - loM)], 1);
  }
  __syncthreads();
  size_t K = (size_t)NF + NM;
  int* cc = cnt + (size_t)c * K;
  for (int j = t; j < NFg; j += 1024) {
    int k = loF + j;
    if (k < hiF) cc[k] = h[j];
  }
  for (int j = t; j < NMg; j += 1024) {
    int k = loM + j;
    if (k < hiM) cc[NF + k] = h[NFg + j];
  }
}

// ---- merged per-key chunk scan (in-place) + degree + chunk-local rowptr scan ----
__global__ __launch_bounds__(256) void k_scan_chunks3(int* __restrict__ cnt, int NF, int NM, int nchf,
                                                      int* __restrict__ rp_f, int* __restrict__ rp_m,
                                                      int* __restrict__ part_f, int* __restrict__ part_m) {
  __shared__ int sm[256];
  int K = NF + NM;
  int t = threadIdx.x;
  bool isM = (int)blockIdx.x >= nchf;
  int b = isM ? (blockIdx.x - nchf) : blockIdx.x;
  int off = isM ? NF : 0;
  int n = isM ? NM : NF;
  int* rowptr = isM ? rp_m : rp_f;
  int* part = isM ? part_m : part_f;
  int base = b * 1024 + t * 4;
  int v0 = 0, v1 = 0, v2 = 0, v3 = 0;
  if (base + 3 < n && (((off + base) & 3) == 0) && ((K & 3) == 0)) {
    int s0 = 0, s1 = 0, s2 = 0, s3 = 0;
    int* p0 = cnt + off + base;
    #pragma unroll 4
    for (int c = 0; c < NB; ++c) {
      int4* p = (int4*)(p0 + (size_t)c * K);
      int4 x = *p;
      *p = make_int4(s0, s1, s2, s3);
      s0 += x.x; s1 += x.y; s2 += x.z; s3 += x.w;
    }
    v0 = s0; v1 = s1; v2 = s2; v3 = s3;
  } else {
    #pragma unroll
    for (int i = 0; i < 4; ++i) {
      int kl = base + i;
      int s = 0;
      if (kl < n) {
        for (int c = 0; c < NB; ++c) {
          int* p = cnt + (size_t)c * K + off + kl;
          int x = *p; *p = s; s += x;
        }
      }
      if (i == 0) v0 = s; else if (i == 1) v1 = s; else if (i == 2) v2 = s; else v3 = s;
    }
  }
  int s = v0 + v1 + v2 + v3;
  sm[t] = s;
  __syncthreads();
  for (int off2 = 1; off2 < 256; off2 <<= 1) {
    int x = (t >= off2) ? sm[t - off2] : 0;
    __syncthreads();
    sm[t] += x;
    __syncthreads();
  }
  int excl = sm[t] - s;
  if (t == 255) part[b] = sm[255];
  if (base + 0 < n) rowptr[base + 0] = excl;
  if (base + 1 < n) rowptr[base + 1] = excl + v0;
  if (base + 2 < n) rowptr[base + 2] = excl + v0 + v1;
  if (base + 3 < n) rowptr[base + 3] = excl + v0 + v1 + v2;
}

// merged part-scan: block 0 -> part_f (nchf entries), block 1 -> part_m
__global__ __launch_bounds__(256) void k_scan_part2(int* __restrict__ part_f, int nchf,
                                                    int* __restrict__ part_m, int nchm) {
  __shared__ int sm[256];
  int t = threadIdx.x;
  int* part = blockIdx.x ? part_m : part_f;
  int nb = blockIdx.x ? nchm : nchf;
  int s = (t < nb) ? part[t] : 0;
  sm[t] = s;
  __syncthreads();
  for (int off = 1; off < 256; off <<= 1) {
    int x = (t >= off) ? sm[t - off] : 0;
    __syncthreads();
    sm[t] += x;
    __syncthreads();
  }
  if (t < nb) part[t] = sm[t] - s;
}

// merged add-off for both rowptrs
__global__ __launch_bounds__(256) void k_add_off2(int* __restrict__ rp_f, const int* __restrict__ part_f, int NF,
                                                  int* __restrict__ rp_m, const int* __restrict__ part_m, int NM,
                                                  int total) {
  int i = blockIdx.x * 256 + threadIdx.x;
  int s = gridDim.x * 256;
  int tot = NF + NM;
  for (; i < tot; i += s) {
    if (i < NF) rp_f[i] += part_f[i >> 10];
    else { int j = i - NF; rp_m[j] += part_m[j >> 10]; }
  }
  if (blockIdx.x == 0 && threadIdx.x == 0) { rp_f[NF] = total; rp_m[NM] = total; }
}

// ---- phase 3: atomic-free scatter via LDS cursors (slots pre-reserved) ----
__global__ __launch_bounds__(1024) void k_scatter2(const int* __restrict__ src, const int* __restrict__ dst,
                                                   const int* __restrict__ rp_f, const int* __restrict__ rp_m,
                                                   const int* __restrict__ cnt,
                                                   int* __restrict__ col_f, int* __restrict__ col_m,
                                                   int E, int NF, int NM) {
  __shared__ int cur[15104];
  int g = blockIdx.x & (NG - 1);
  int c = blockIdx.x >> 3;
  int t = threadIdx.x;
  int NFg = (NF + NG - 1) / NG, NMg = (NM + NG - 1) / NG;
  int loF = g * NFg, hiF = dmin(NF, loF + NFg);
  int loM = g * NMg, hiM = dmin(NM, loM + NMg);
  size_t K = (size_t)NF + NM;
  const int* cc = cnt + (size_t)c * K;
  for (int j = t; j < NFg; j += 1024) {
    int k = loF + j;
    if (k < hiF) cur[j] = rp_f[k] + cc[k];
  }
  for (int j = t; j < NMg; j += 1024) {
    int k = loM + j;
    if (k < hiM) cur[NFg + j] = rp_m[k] + cc[NF + k];
  }
  __syncthreads();
  int Epc = (E + NB - 1) / NB;
  int c0 = c * Epc, c1 = dmin(E, c0 + Epc);
  for (int i = c0 + t; i < c1; i += 1024) {
    int s = src[i], d = dst[i];
    if (s >= loF && s < hiF) {
      int p = atomicAdd(&cur[s - loF], 1);
      col_f[p] = d;
    }
    if (d >= loM && d < hiM) {
      int p = atomicAdd(&cur[NFg + (d - loM)], 1);
      col_m[p] = s;
    }
  }
}

// merged: weight f32->bf16 conversion (106496 elems) + input projections
__global__ __launch_bounds__(256) void k_projw(const float* __restrict__ xf, const float* __restrict__ Wf,
                                               const float* __restrict__ bfp, const float* __restrict__ xm,
                                               const float* __restrict__ Wm, const float* __restrict__ bmp,
                                               u16* __restrict__ outf, u16* __restrict__ outm,
                                               int NF, int NM,
                                               const float* __restrict__ s0, const float* __restrict__ s1,
                                               const float* __restrict__ s2, const float* __restrict__ s3,
                                               const float* __restrict__ s4, const float* __restrict__ s5,
                                               const float* __restrict__ s6, u16* __restrict__ wdst) {
  __shared__ float Wfs[128 * 9];
  __shared__ float Wms[128 * 5];
  __shared__ float bsf[128];
  __shared__ float bsm[128];
  int t = threadIdx.x;
  for (int i = t; i < 128 * 8; i += 256) {
    int c = i >> 3, k = i & 7;
    Wfs[c * 9 + k] = Wf[i];
  }
  for (int i = t; i < 128 * 5; i += 256) {
    int c = i / 5, k = i - c * 5;
    Wms[c * 5 + k] = Wm[i];
  }
  for (int i = t; i < 128; i += 256) { bsf[i] = bfp[i]; bsm[i] = bmp[i]; }
  __syncthreads();
  const int W2N = 106496;
  int totF = NF * 64;
  int tot = W2N + totF + NM * 64;
  int idx = blockIdx.x * 256 + t;
  int gs = gridDim.x * 256;
  for (; idx < tot; idx += gs) {
    if (idx < W2N) {
      int i = idx;
      const float* s; int off = i;
      if (i < 16384) { s = s0; }
      else if (i < 32768) { s = s1; off = i - 16384; }
      else if (i < 49152) { s = s2; off = i - 32768; }
      else if (i < 65536) { s = s3; off = i - 49152; }
      else if (i < 81920) { s = s4; off = i - 65536; }
      else if (i < 98304) { s = s5; off = i - 81920; }
      else { s = s6; off = i - 98304; }
      wdst[i] = f2bf(s[off]);
    } else if (idx < W2N + totF) {
      int k2 = idx - W2N;
      int row = k2 >> 6, cp = (k2 & 63) * 2;
      float a0 = bsf[cp], a1 = bsf[cp + 1];
      const float* xr = xf + (size_t)row * 8;
      #pragma unroll
      for (int k = 0; k < 8; ++k) {
        float xv = xr[k];
        a0 += Wfs[cp * 9 + k] * xv;
        a1 += Wfs[(cp + 1) * 9 + k] * xv;
      }
      a0 = fmaxf(a0, 0.f); a1 = fmaxf(a1, 0.f);
      u32 pk = (u32)f2bf(a0) | ((u32)f2bf(a1) << 16);
      *(u32*)(outf + (size_t)row * HDIM + cp) = pk;
    } else {
      int k2 = idx - W2N - totF;
      int row = k2 >> 6, cp = (k2 & 63) * 2;
      float a0 = bsm[cp], a1 = bsm[cp + 1];
      const float* xr = xm + (size_t)row * 5;
      #pragma unroll
      for (int k = 0; k < 5; ++k) {
        float xv = xr[k];
        a0 += Wms[cp * 5 + k] * xv;
        a1 += Wms[(cp + 1) * 5 + k] * xv;
      }
      a0 = fmaxf(a0, 0.f); a1 = fmaxf(a1, 0.f);
      u32 pk = (u32)f2bf(a0) | ((u32)f2bf(a1) << 16);
      *(u32*)(outm + (size_t)row * HDIM + cp) = pk;
    }
  }
}

// Mean aggregation, 16-lane groups, 256B rows (fund->manager agg)
__global__ __launch_bounds__(256) void k_agg2(const u16* __restrict__ feat, const int* __restrict__ rowptr,
                                              const int* __restrict__ col, u16* __restrict__ out, int ndst) {
  int t = threadIdx.x;
  int grp = t >> 4, lc = t & 15;
  int nd = blockIdx.x * 16 + grp;
  if (nd >= ndst) return;
  int s0 = rowptr[nd], s1 = rowptr[nd + 1];
  float a0=0.f,a1=0.f,a2=0.f,a3=0.f,a4=0.f,a5=0.f,a6=0.f,a7=0.f;
  const u16* fb = feat + lc * 8;
  int j = s0;
  for (; j + 3 < s1; j += 4) {
    uint4 v0 = *(const uint4*)(fb + (size_t)col[j]     * HDIM);
    uint4 v1 = *(const uint4*)(fb + (size_t)col[j + 1] * HDIM);
    uint4 v2 = *(const uint4*)(fb + (size_t)col[j + 2] * HDIM);
    uint4 v3 = *(const uint4*)(fb + (size_t)col[j + 3] * HDIM);
    a0 += bf2f((u16)v0.x) + bf2f((u16)v1.x) + bf2f((u16)v2.x) + bf2f((u16)v3.x);
    a1 += bf2f((u16)(v0.x>>16)) + bf2f((u16)(v1.x>>16)) + bf2f((u16)(v2.x>>16)) + bf2f((u16)(v3.x>>16));
    a2 += bf2f((u16)v0.y) + bf2f((u16)v1.y) + bf2f((u16)v2.y) + bf2f((u16)v3.y);
    a3 += bf2f((u16)(v0.y>>16)) + bf2f((u16)(v1.y>>16)) + bf2f((u16)(v2.y>>16)) + bf2f((u16)(v3.y>>16));
    a4 += bf2f((u16)v0.z) + bf2f((u16)v1.z) + bf2f((u16)v2.z) + bf2f((u16)v3.z);
    a5 += bf2f((u16)(v0.z>>16)) + bf2f((u16)(v1.z>>16)) + bf2f((u16)(v2.z>>16)) + bf2f((u16)(v3.z>>16));
    a6 += bf2f((u16)v0.w) + bf2f((u16)v1.w) + bf2f((u16)v2.w) + bf2f((u16)v3.w);
    a7 += bf2f((u16)(v0.w>>16)) + bf2f((u16)(v1.w>>16)) + bf2f((u16)(v2.w>>16)) + bf2f((u16)(v3.w>>16));
  }
  for (; j < s1; ++j) {
    uint4 v = *(const uint4*)(fb + (size_t)col[j] * HDIM);
    a0 += bf2f((u16)v.x); a1 += bf2f((u16)(v.x >> 16));
    a2 += bf2f((u16)v.y); a3 += bf2f((u16)(v.y >> 16));
    a4 += bf2f((u16)v.z); a5 += bf2f((u16)(v.z >> 16));
    a6 += bf2f((u16)v.w); a7 += bf2f((u16)(v.w >> 16));
  }
  float inv = (s1 > s0) ? 1.f / (float)(s1 - s0) : 0.f;
  uint4 pk;
  pk.x = (u32)f2bf(a0 * inv) | ((u32)f2bf(a1 * inv) << 16);
  pk.y = (u32)f2bf(a2 * inv) | ((u32)f2bf(a3 * inv) << 16);
  pk.z = (u32)f2bf(a4 * inv) | ((u32)f2bf(a5 * inv) << 16);
  pk.w = (u32)f2bf(a6 * inv) | ((u32)f2bf(a7 * inv) << 16);
  *(uint4*)(out + (size_t)nd * HDIM + lc * 8) = pk;
}

// Dual mean aggregation over interleaved [t0|t1] 512B rows; 32-lane groups,
// unroll-4. At the L2<->L3 fabric roofline (~3.9 TB/s for random 512B rows):
// fusion (R5), per-block phasing (R8), XCD-affine slicing (R10), unroll-8
// (R11) all failed to beat this form.
__global__ __launch_bounds__(256) void k_aggd(const u16* __restrict__ tc, const int* __restrict__ rowptr,
                                              const int* __restrict__ col, u16* __restrict__ aggc, int ndst) {
  int t = threadIdx.x;
  int grp = t >> 5, lc = t & 31;
  int nd = blockIdx.x * 8 + grp;
  if (nd >= ndst) return;
  int s0 = rowptr[nd], s1 = rowptr[nd + 1];
  float a0=0.f,a1=0.f,a2=0.f,a3=0.f,a4=0.f,a5=0.f,a6=0.f,a7=0.f;
  const u16* fb = tc + lc * 8;
  int j = s0;
  for (; j + 3 < s1; j += 4) {
    uint4 v0 = *(const uint4*)(fb + (size_t)col[j]     * 256);
    uint4 v1 = *(const uint4*)(fb + (size_t)col[j + 1] * 256);
    uint4 v2 = *(const uint4*)(fb + (size_t)col[j + 2] * 256);
    uint4 v3 = *(const uint4*)(fb + (size_t)col[j + 3] * 256);
    a0 += bf2f((u16)v0.x) + bf2f((u16)v1.x) + bf2f((u16)v2.x) + bf2f((u16)v3.x);
    a1 += bf2f((u16)(v0.x>>16)) + bf2f((u16)(v1.x>>16)) + bf2f((u16)(v2.x>>16)) + bf2f((u16)(v3.x>>16));
    a2 += bf2f((u16)v0.y) + bf2f((u16)v1.y) + bf2f((u16)v2.y) + bf2f((u16)v3.y);
    a3 += bf2f((u16)(v0.y>>16)) + bf2f((u16)(v1.y>>16)) + bf2f((u16)(v2.y>>16)) + bf2f((u16)(v3.y>>16));
    a4 += bf2f((u16)v0.z) + bf2f((u16)v1.z) + bf2f((u16)v2.z) + bf2f((u16)v3.z);
    a5 += bf2f((u16)(v0.z>>16)) + bf2f((u16)(v1.z>>16)) + bf2f((u16)(v2.z>>16)) + bf2f((u16)(v3.z>>16));
    a6 += bf2f((u16)v0.w) + bf2f((u16)v1.w) + bf2f((u16)v2.w) + bf2f((u16)v3.w);
    a7 += bf2f((u16)(v0.w>>16)) + bf2f((u16)(v1.w>>16)) + bf2f((u16)(v2.w>>16)) + bf2f((u16)(v3.w>>16));
  }
  for (; j < s1; ++j) {
    uint4 v = *(const uint4*)(fb + (size_t)col[j] * 256);
    a0 += bf2f((u16)v.x); a1 += bf2f((u16)(v.x >> 16));
    a2 += bf2f((u16)v.y); a3 += bf2f((u16)(v.y >> 16));
    a4 += bf2f((u16)v.z); a5 += bf2f((u16)(v.z >> 16));
    a6 += bf2f((u16)v.w); a7 += bf2f((u16)(v.w >> 16));
  }
  float inv = (s1 > s0) ? 1.f / (float)(s1 - s0) : 0.f;
  uint4 pk;
  pk.x = (u32)f2bf(a0 * inv) | ((u32)f2bf(a1 * inv) << 16);
  pk.y = (u32)f2bf(a2 * inv) | ((u32)f2bf(a3 * inv) << 16);
  pk.z = (u32)f2bf(a4 * inv) | ((u32)f2bf(a5 * inv) << 16);
  pk.w = (u32)f2bf(a6 * inv) | ((u32)f2bf(a7 * inv) << 16);
  *(uint4*)(aggc + (size_t)nd * 256 + lc * 8) = pk;
}

// MFMA GEMM, swapped operands (A=W, B=X): lane owns one output row, 4 cols/nt.
__global__ __launch_bounds__(256) void k_ling(const u16* __restrict__ X1, const u16* __restrict__ W1,
                                              const u16* __restrict__ X2, const u16* __restrict__ W2,
                                              const u16* __restrict__ ADD, const float* __restrict__ bias,
                                              u16* __restrict__ out, int n, int do_relu,
                                              int ostride, int astride) {
  int t = threadIdx.x;
  int w = t >> 6, lane = t & 63;
  int lm = lane & 15, lk = (lane >> 4) * 8;
  int cg = (lane >> 4) * 4;
  int row0 = blockIdx.x * 128 + w * 32;
  if (row0 >= n) return;
  int r0 = row0 + lm;       if (r0 >= n) r0 = n - 1;
  int r1 = row0 + 16 + lm;  if (r1 >= n) r1 = n - 1;
  f32x4 acc0[8], acc1[8];
  #pragma unroll
  for (int i = 0; i < 8; ++i) { acc0[i] = (f32x4){0.f,0.f,0.f,0.f}; acc1[i] = (f32x4){0.f,0.f,0.f,0.f}; }
  const u16* Xp = X1;
  const u16* Wp = W1;
  for (int p = 0; p < 2; ++p) {
    #pragma unroll
    for (int ks = 0; ks < 4; ++ks) {
      bf16x8 b0 = *(const bf16x8*)(Xp + (size_t)r0 * 128 + ks * 32 + lk);
      bf16x8 b1 = *(const bf16x8*)(Xp + (size_t)r1 * 128 + ks * 32 + lk);
      #pragma unroll
      for (int nt = 0; nt < 8; ++nt) {
        bf16x8 a = *(const bf16x8*)(Wp + (size_t)(nt * 16 + lm) * 128 + ks * 32 + lk);
        acc0[nt] = __builtin_amdgcn_mfma_f32_16x16x32_bf16(a, b0, acc0[nt], 0, 0, 0);
        acc1[nt] = __builtin_amdgcn_mfma_f32_16x16x32_bf16(a, b1, acc1[nt], 0, 0, 0);
      }
    }
    if (!X2) break;
    Xp = X2;
    Wp = W2;
  }
  #pragma unroll
  for (int half = 0; half < 2; ++half) {
    int m = row0 + half * 16 + lm;
    if (m >= n) break;
    f32x4* acc = half ? acc1 : acc0;
    #pragma unroll
    for (int nt = 0; nt < 8; ++nt) {
      int c = nt * 16 + cg;
      float v0 = acc[nt][0], v1 = acc[nt][1], v2 = acc[nt][2], v3 = acc[nt][3];
      if (bias) {
        float4 bv = *(const float4*)(bias + c);
        v0 += bv.x; v1 += bv.y; v2 += bv.z; v3 += bv.w;
      }
      if (ADD) {
        ushort4 av = *(const ushort4*)(ADD + (size_t)m * astride + c);
        v0 += bf2f(av.x); v1 += bf2f(av.y); v2 += bf2f(av.z); v3 += bf2f(av.w);
      }
      if (do_relu) {
        v0 = fmaxf(v0, 0.f); v1 = fmaxf(v1, 0.f); v2 = fmaxf(v2, 0.f); v3 = fmaxf(v3, 0.f);
      }
      ushort4 pk;
      pk.x = f2bf(v0); pk.y = f2bf(v1); pk.z = f2bf(v2); pk.w = f2bf(v3);
      *(ushort4*)(out + (size_t)m * ostride + c) = pk;
    }
  }
}

// Two independent no-bias GEMMs into interleaved [n][256] buffer.
__global__ __launch_bounds__(256) void k_ling2(const u16* __restrict__ XA, const u16* __restrict__ WA,
                                               const u16* __restrict__ XB, const u16* __restrict__ WB,
                                               u16* __restrict__ out, int n) {
  int nb = gridDim.x >> 1;
  bool second = (int)blockIdx.x >= nb;
  const u16* X = second ? XB : XA;
  const u16* W = second ? WB : WA;
  int bid = second ? (blockIdx.x - nb) : blockIdx.x;
  u16* o = out + (second ? 128 : 0);
  int t = threadIdx.x;
  int w = t >> 6, lane = t & 63;
  int lm = lane & 15, lk = (lane >> 4) * 8;
  int cg = (lane >> 4) * 4;
  int row0 = bid * 128 + w * 32;
  if (row0 >= n) return;
  int r0 = row0 + lm;       if (r0 >= n) r0 = n - 1;
  int r1 = row0 + 16 + lm;  if (r1 >= n) r1 = n - 1;
  f32x4 acc0[8], acc1[8];
  #pragma unroll
  for (int i = 0; i < 8; ++i) { acc0[i] = (f32x4){0.f,0.f,0.f,0.f}; acc1[i] = (f32x4){0.f,0.f,0.f,0.f}; }
  #pragma unroll
  for (int ks = 0; ks < 4; ++ks) {
    bf16x8 b0 = *(const bf16x8*)(X + (size_t)r0 * 128 + ks * 32 + lk);
    bf16x8 b1 = *(const bf16x8*)(X + (size_t)r1 * 128 + ks * 32 + lk);
    #pragma unroll
    for (int nt = 0; nt < 8; ++nt) {
      bf16x8 a = *(const bf16x8*)(W + (size_t)(nt * 16 + lm) * 128 + ks * 32 + lk);
      acc0[nt] = __builtin_amdgcn_mfma_f32_16x16x32_bf16(a, b0, acc0[nt], 0, 0, 0);
      acc1[nt] = __builtin_amdgcn_mfma_f32_16x16x32_bf16(a, b1, acc1[nt], 0, 0, 0);
    }
  }
  #pragma unroll
  for (int half = 0; half < 2; ++half) {
    int m = row0 + half * 16 + lm;
    if (m >= n) break;
    f32x4* acc = half ? acc1 : acc0;
    #pragma unroll
    for (int nt = 0; nt < 8; ++nt) {
      int c = nt * 16 + cg;
      ushort4 pk;
      pk.x = f2bf(acc[nt][0]); pk.y = f2bf(acc[nt][1]);
      pk.z = f2bf(acc[nt][2]); pk.w = f2bf(acc[nt][3]);
      *(ushort4*)(o + (size_t)m * 256 + c) = pk;
    }
  }
}

// Fused f2-GEMM + classifier: f2 tile lives only in per-wave LDS (never HBM).
__global__ __launch_bounds__(256) void k_lingcls(const u16* __restrict__ X1, const u16* __restrict__ W1,
                                                 const u16* __restrict__ ADD, const float* __restrict__ bias,
                                                 const u16* __restrict__ Wc1bf, const float* __restrict__ bc1,
                                                 const float* __restrict__ Wc2, const float* __restrict__ bc2,
                                                 float* __restrict__ out, int n) {
  __shared__ u16 tile[4][32][136];
  int t = threadIdx.x;
  int w = t >> 6, lane = t & 63;
  int lm = lane & 15, lk = (lane >> 4) * 8;
  int cg = (lane >> 4) * 4;
  int row0 = blockIdx.x * 128 + w * 32;
  if (row0 >= n) return;
  int r0 = row0 + lm;       if (r0 >= n) r0 = n - 1;
  int r1 = row0 + 16 + lm;  if (r1 >= n) r1 = n - 1;
  f32x4 acc0[8], acc1[8];
  #pragma unroll
  for (int i = 0; i < 8; ++i) { acc0[i] = (f32x4){0.f,0.f,0.f,0.f}; acc1[i] = (f32x4){0.f,0.f,0.f,0.f}; }
  #pragma unroll
  for (int ks = 0; ks < 4; ++ks) {
    bf16x8 b0 = *(const bf16x8*)(X1 + (size_t)r0 * 128 + ks * 32 + lk);
    bf16x8 b1 = *(const bf16x8*)(X1 + (size_t)r1 * 128 + ks * 32 + lk);
    #pragma unroll
    for (int nt = 0; nt < 8; ++nt) {
      bf16x8 a = *(const bf16x8*)(W1 + (size_t)(nt * 16 + lm) * 128 + ks * 32 + lk);
      acc0[nt] = __builtin_amdgcn_mfma_f32_16x16x32_bf16(a, b0, acc0[nt], 0, 0, 0);
      acc1[nt] = __builtin_amdgcn_mfma_f32_16x16x32_bf16(a, b1, acc1[nt], 0, 0, 0);
    }
  }
  #pragma unroll
  for (int half = 0; half < 2; ++half) {
    int m = row0 + half * 16 + lm;
    if (m >= n) break;
    int lr = half * 16 + lm;
    f32x4* acc = half ? acc1 : acc0;
    #pragma unroll
    for (int nt = 0; nt < 8; ++nt) {
      int c = nt * 16 + cg;
      float4 bv = *(const float4*)(bias + c);
      ushort4 av = *(const ushort4*)(ADD + (size_t)m * 256 + c);
      float v0 = fmaxf(acc[nt][0] + bv.x + bf2f(av.x), 0.f);
      float v1 = fmaxf(acc[nt][1] + bv.y + bf2f(av.y), 0.f);
      float v2 = fmaxf(acc[nt][2] + bv.z + bf2f(av.z), 0.f);
      float v3 = fmaxf(acc[nt][3] + bv.w + bf2f(av.w), 0.f);
      ushort4 pk;
      pk.x = f2bf(v0); pk.y = f2bf(v1); pk.z = f2bf(v2); pk.w = f2bf(v3);
      *(ushort4*)&tile[w][lr][c] = pk;
    }
  }
  #pragma unroll
  for (int half = 0; half < 2; ++half) {
    f32x4 cacc[4];
    #pragma unroll
    for (int i = 0; i < 4; ++i) cacc[i] = (f32x4){0.f, 0.f, 0.f, 0.f};
    #pragma unroll
    for (int ks = 0; ks < 4; ++ks) {
      bf16x8 b = *(const bf16x8*)&tile[w][half * 16 + lm][ks * 32 + lk];
      #pragma unroll
      for (int nt = 0; nt < 4; ++nt) {
        bf16x8 a = *(const bf16x8*)(Wc1bf + (size_t)(nt * 16 + lm) * 128 + ks * 32 + lk);
        cacc[nt] = __builtin_amdgcn_mfma_f32_16x16x32_bf16(a, b, cacc[nt], 0, 0, 0);
      }
    }
    float s0 = 0.f, s1 = 0.f;
    #pragma unroll
    for (int nt = 0; nt < 4; ++nt) {
      int k = nt * 16 + cg;
      float4 bv = *(const float4*)(bc1 + k);
      float4 w0 = *(const float4*)(Wc2 + k);
      float4 w1 = *(const float4*)(Wc2 + 64 + k);
      float h0 = fmaxf(cacc[nt][0] + bv.x, 0.f);
      float h1 = fmaxf(cacc[nt][1] + bv.y, 0.f);
      float h2 = fmaxf(cacc[nt][2] + bv.z, 0.f);
      float h3 = fmaxf(cacc[nt][3] + bv.w, 0.f);
      s0 += h0 * w0.x + h1 * w0.y + h2 * w0.z + h3 * w0.w;
      s1 += h0 * w1.x + h1 * w1.y + h2 * w1.z + h3 * w1.w;
    }
    s0 += __shfl_xor(s0, 16); s1 += __shfl_xor(s1, 16);
    s0 += __shfl_xor(s0, 32); s1 += __shfl_xor(s1, 32);
    int m = row0 + half * 16 + lm;
    if (lane < 16 && m < n) {
      out[(size_t)m * 2 + 0] = s0 + bc2[0];
      out[(size_t)m * 2 + 1] = s1 + bc2[1];
    }
  }
}

static inline int imin(int a, int b) { return a < b ? a : b; }

extern "C" void kernel_launch(void* const* d_in, const int* in_sizes, int n_in,
                              void* d_out, int out_size, void* d_ws, size_t ws_size,
                              hipStream_t stream) {
  const float* x_fund = (const float*)d_in[0];
  const float* x_mgr  = (const float*)d_in[1];
  const int* fm_src   = (const int*)d_in[2];
  const int* fm_dst   = (const int*)d_in[3];
  const float* Wf = (const float*)d_in[4];
  const float* bfb = (const float*)d_in[5];
  const float* Wm = (const float*)d_in[6];
  const float* bm = (const float*)d_in[7];
  const float* Wl_fm0 = (const float*)d_in[8];
  const float* bl_fm0 = (const float*)d_in[9];
  const float* Wr_fm0 = (const float*)d_in[10];
  const float* Wl_mf0 = (const float*)d_in[11];
  const float* bl_mf0 = (const float*)d_in[12];
  const float* Wr_mf0 = (const float*)d_in[13];
  const float* Wl_mf1 = (const float*)d_in[17];
  const float* bl_mf1 = (const float*)d_in[18];
  const float* Wr_mf1 = (const float*)d_in[19];
  const float* Wc1 = (const float*)d_in[20];
  const float* bc1 = (const float*)d_in[21];
  const float* Wc2 = (const float*)d_in[22];
  const float* bc2 = (const float*)d_in[23];
  // (Wl_fm1/bl_fm1/Wr_fm1 at indices 14..16 are dead: m2 is deleted in the reference)

  int NF = in_sizes[0] / 8;
  int NM = in_sizes[1] / 5;
  int E  = in_sizes[2];
  int K  = NF + NM;

  char* ws = (char*)d_ws;
  size_t off = 0;
  auto alloc = [&](size_t bytes) -> char* {
    char* p = ws + off;
    off += (bytes + 255) & ~(size_t)255;
    return p;
  };
  u16* f_b   = (u16*)alloc((size_t)NF * HDIM * 2);
  u16* f1_b  = (u16*)alloc((size_t)NF * HDIM * 2);
  u16* aggc  = (u16*)alloc((size_t)NF * 256 * 2);   // interleaved [aggf0|aggf1]
  u16* m_b   = (u16*)alloc((size_t)NM * HDIM * 2);
  u16* m1_b  = (u16*)alloc((size_t)NM * HDIM * 2);
  u16* tcomb = (u16*)alloc((size_t)NM * 256 * 2);   // interleaved [t0|t1]
  u16* aggm  = (u16*)alloc((size_t)NM * HDIM * 2);
  u16* wbf   = (u16*)alloc((size_t)106496 * 2);
  int* rp_f  = (int*)alloc((size_t)(NF + 1) * 4);
  int* rp_m  = (int*)alloc((size_t)(NM + 1) * 4);
  int* col_f = (int*)alloc((size_t)E * 4);
  int* col_m = (int*)alloc((size_t)E * 4);
  int* cnt   = (int*)alloc((size_t)NB * K * 4);
  int* part_f = (int*)alloc(256 * 4);
  int* part_m = (int*)alloc(256 * 4);
  (void)ws_size; (void)n_in; (void)out_size;

  u16* Wlfm0b = wbf + 0;
  u16* Wrfm0b = wbf + 16384;
  u16* Wlmf0b = wbf + 32768;
  u16* Wrmf0b = wbf + 49152;
  u16* Wlmf1b = wbf + 65536;
  u16* Wrmf1b = wbf + 81920;
  u16* Wc1b   = wbf + 98304;

  int nch_f = (NF + 1023) / 1024;
  int nch_m = (NM + 1023) / 1024;

  // ---- atomic-free CSR build (merged scan pipeline) ----
  k_hist2<<<NG * NB, 1024, 0, stream>>>(fm_src, fm_dst, cnt, E, NF, NM);
  k_scan_chunks3<<<nch_f + nch_m, 256, 0, stream>>>(cnt, NF, NM, nch_f, rp_f, rp_m, part_f, part_m);
  k_scan_part2<<<2, 256, 0, stream>>>(part_f, nch_f, part_m, nch_m);
  k_add_off2<<<(K + 255) / 256, 256, 0, stream>>>(rp_f, part_f, NF, rp_m, part_m, NM, E);
  k_scatter2<<<NG * NB, 1024, 0, stream>>>(fm_src, fm_dst, rp_f, rp_m, cnt, col_f, col_m, E, NF, NM);

  // ---- merged weight conversion + input projections ----
  k_projw<<<4096, 256, 0, stream>>>(x_fund, Wf, bfb, x_mgr, Wm, bm, f_b, m_b, NF, NM,
                                    Wl_fm0, Wr_fm0, Wl_mf0, Wr_mf0, Wl_mf1, Wr_mf1, Wc1, wbf);

  // ---- layer 0, fund->manager: m1 = relu(agg(f)@Wl + m@Wr + bl) ----
  k_agg2<<<(NM + 15) / 16, 256, 0, stream>>>(f_b, rp_m, col_m, aggm, NM);
  k_ling<<<(NM + 127) / 128, 256, 0, stream>>>(aggm, Wlfm0b, m_b, Wrfm0b, nullptr, bl_fm0,
                                               m1_b, NM, 1, 128, 128);

  // ---- t0 = m@Wl_mf0, t1 = m1@Wl_mf1 -> interleaved tcomb (one launch) ----
  k_ling2<<<2 * ((NM + 127) / 128), 256, 0, stream>>>(m_b, Wlmf0b, m1_b, Wlmf1b, tcomb, NM);

  // ---- dual gather, unroll-4 (L3 fabric roofline) ----
  k_aggd<<<(NF + 7) / 8, 256, 0, stream>>>(tcomb, rp_f, col_f, aggc, NF);

  // ---- f1 = relu(f@Wr_mf0 + aggf0 + bl0) ----
  k_ling<<<(NF + 127) / 128, 256, 0, stream>>>(f_b, Wrmf0b, nullptr, nullptr, aggc, bl_mf0,
                                               f1_b, NF, 1, 128, 256);

  // ---- fused: f2 = relu(f1@Wr_mf1 + aggf1 + bl1) -> LDS -> classifier -> out ----
  k_lingcls<<<(NF + 127) / 128, 256, 0, stream>>>(f1_b, Wrmf1b, aggc + 128, bl_mf1,
                                                  Wc1b, bc1, Wc2, bc2, (float*)d_out, NF);
}